// Round 4
// baseline (555.791 us; speedup 1.0000x reference)
//
#include <hip/hip_runtime.h>
#include <stdint.h>

#define DIM 2048

typedef short short8 __attribute__((ext_vector_type(8)));
typedef float f32x4 __attribute__((ext_vector_type(4)));

__device__ __forceinline__ unsigned short f2bf(float f) {
    union { float f; unsigned int u; } v;
    v.f = f;
    unsigned int r = v.u + 0x7FFFu + ((v.u >> 16) & 1u);  // round-to-nearest-even
    return (unsigned short)(r >> 16);
}
__device__ __forceinline__ float bf2f(unsigned short u) {
    union { unsigned int u; float f; } v;
    v.u = ((unsigned int)u) << 16;
    return v.f;
}

// async global->LDS, 16B per lane. LDS dest must be wave-uniform base + lane*16.
__device__ __forceinline__ void async16(const unsigned short* g, unsigned short* l) {
    __builtin_amdgcn_global_load_lds(
        (__attribute__((address_space(1))) void*)(uintptr_t)g,
        (__attribute__((address_space(3))) void*)(uintptr_t)l,
        16, 0, 0);
}

// Tiled skew-symmetric build: one block per upper-tri 64x64 tile pair.
__global__ __launch_bounds__(256) void build_A_tiled(const float* __restrict__ ang,
                                                     unsigned short* __restrict__ A) {
    __shared__ float tile[64][65];
    int b = blockIdx.x;
    int ti = 0, rem = b;
    while (rem >= 32 - ti) { rem -= 32 - ti; ++ti; }
    const int tj = ti + rem;
    const int t  = threadIdx.x;
    const int lj = t & 63;
    const int lw = t >> 6;
    const bool diag = (ti == tj);

#pragma unroll
    for (int m = 0; m < 16; ++m) {
        const int li = lw * 16 + m;
        const int i = ti * 64 + li;
        const int j = tj * 64 + lj;
        float v = 0.0f;
        if (i < j) v = ang[i * (4095 - i) / 2 + (j - i - 1)];
        tile[li][lj] = v;
    }
    __syncthreads();

#pragma unroll
    for (int m = 0; m < 16; ++m) {
        const int li = lw * 16 + m;
        float v;
        if (diag) {
            if (li < lj)      v =  tile[li][lj];
            else if (li > lj) v = -tile[lj][li];
            else              v = 0.0f;
        } else {
            v = tile[li][lj];
        }
        A[(size_t)(ti * 64 + li) * DIM + tj * 64 + lj] = f2bf(v);
    }
    if (!diag) {
#pragma unroll
        for (int m = 0; m < 16; ++m) {
            const int li = lw * 16 + m;
            A[(size_t)(tj * 64 + li) * DIM + ti * 64 + lj] = f2bf(-tile[lj][li]);
        }
    }
}

// fp32 -> bf16, 4 elems/thread
__global__ void cvt_f32_bf16(const float* __restrict__ in, unsigned short* __restrict__ out) {
    int i = (blockIdx.x * 256 + threadIdx.x) * 4;
    const float4 v = *(const float4*)(in + i);
    ushort4 o;
    o.x = f2bf(v.x); o.y = f2bf(v.y); o.z = f2bf(v.z); o.w = f2bf(v.w);
    *(ushort4*)(out + i) = o;
}

// Wt builder: Wt[m*N+n] = (m==n) - 2*A[m*N+n] - sum_k A[m][k]*A[n][k]
__global__ __launch_bounds__(256) void gemm_s64(
        const unsigned short* __restrict__ A,
        unsigned short* __restrict__ Wt) {
    __shared__ __align__(16) unsigned short ldsA[64 * 64];
    __shared__ __align__(16) unsigned short ldsB[64 * 64];
    const int K = DIM, N = DIM;

    const int t    = threadIdx.x;
    const int bn   = blockIdx.x * 64;
    const int bm   = blockIdx.y * 64;
    const int lane = t & 63;
    const int wave = t >> 6;
    const int waveM = (wave >> 1) * 32;
    const int waveN = (wave & 1) * 32;
    const int fm = lane & 15;
    const int fq = lane >> 4;

    f32x4 acc[2][2];
#pragma unroll
    for (int i = 0; i < 2; ++i)
#pragma unroll
        for (int j = 0; j < 2; ++j)
            acc[i][j] = (f32x4){0.f, 0.f, 0.f, 0.f};

    const int trow   = t >> 3;
    const int tchunk = (t & 7) ^ (trow & 7);
    const unsigned short* gA = A + (size_t)(bm + trow) * K + tchunk * 8;
    const unsigned short* gB = A + (size_t)(bn + trow) * K + tchunk * 8;
    const size_t rowskip = (size_t)32 * K;
    unsigned short* lA = ldsA + t * 8;
    unsigned short* lB = ldsB + t * 8;

    for (int kt = 0; kt < K; kt += 64) {
        __syncthreads();
        async16(gA + kt, lA);
        async16(gA + kt + rowskip, lA + 2048);
        async16(gB + kt, lB);
        async16(gB + kt + rowskip, lB + 2048);
        __syncthreads();

#pragma unroll
        for (int ks = 0; ks < 2; ++ks) {
            short8 af[2], bfv[2];
#pragma unroll
            for (int i = 0; i < 2; ++i) {
                const int rowA = waveM + i * 16 + fm;
                const int rowB = waveN + i * 16 + fm;
                af[i]  = *(const short8*)(ldsA + rowA * 64 + (((ks << 2) + fq) ^ (rowA & 7)) * 8);
                bfv[i] = *(const short8*)(ldsB + rowB * 64 + (((ks << 2) + fq) ^ (rowB & 7)) * 8);
            }
#pragma unroll
            for (int i = 0; i < 2; ++i)
#pragma unroll
                for (int j = 0; j < 2; ++j)
                    acc[i][j] = __builtin_amdgcn_mfma_f32_16x16x32_bf16(
                        af[i], bfv[j], acc[i][j], 0, 0, 0);
        }
    }

#pragma unroll
    for (int i = 0; i < 2; ++i) {
#pragma unroll
        for (int j = 0; j < 2; ++j) {
            const int col = bn + waveN + j * 16 + fm;
#pragma unroll
            for (int r = 0; r < 4; ++r) {
                const int row = bm + waveM + i * 16 + fq * 4 + r;
                const float a = bf2f(A[(size_t)row * N + col]);
                const float w = (row == col ? 1.0f : 0.0f) - 2.0f * a - acc[i][j][r];
                Wt[(size_t)row * N + col] = f2bf(w);
            }
        }
    }
}

// Main NT GEMM: out[m*N+n] = sum_k X[m][k]*Wt[n][k] + bias[n]
// LDS-traffic-minimized: A (x) staged via double-buffered async16 LDS (one
// barrier per BK=64); B (Wt) fragments loaded DIRECTLY from global (L2/L3
// resident, full-cache-line wave pattern), ping-pong register prefetch one
// K-iteration ahead. LDS/iter drops 96KB->48KB (was the bottleneck pipe).
__global__ __launch_bounds__(256) void gemm_main(
        const unsigned short* __restrict__ X,
        const unsigned short* __restrict__ Wt,
        int M, int N, int K,
        const float* __restrict__ bias,
        float* __restrict__ out) {
    __shared__ __align__(16) unsigned short ldsA[2][128 * 64];   // 32 KB dbuf

    const int t    = threadIdx.x;
    const int bn   = blockIdx.x * 128;
    const int bm   = blockIdx.y * 128;
    const int lane = t & 63;
    const int wave = t >> 6;
    const int waveM = (wave >> 1) * 64;
    const int waveN = (wave & 1) * 64;
    const int fm = lane & 15;
    const int fq = lane >> 4;

    f32x4 acc[4][4];
#pragma unroll
    for (int i = 0; i < 4; ++i)
#pragma unroll
        for (int j = 0; j < 4; ++j)
            acc[i][j] = (f32x4){0.f, 0.f, 0.f, 0.f};

    // A staging (XOR-swizzled, conflict-free — verified 0 conflicts R2/R3)
    const int trow   = t >> 3;
    const int tchunk = (t & 7) ^ (trow & 7);
    const unsigned short* gA = X + (size_t)(bm + trow) * K + tchunk * 8;
    const size_t rowskip = (size_t)32 * K;

    // B fragment base pointers: col = bn + waveN + j*16 + fm, k-chunk fq*8
    const unsigned short* bp[4];
#pragma unroll
    for (int j = 0; j < 4; ++j)
        bp[j] = Wt + (size_t)(bn + waveN + j * 16 + fm) * K + fq * 8;

    auto stageA = [&](int kt, int p) {
        unsigned short* l = &ldsA[p][t * 8];
#pragma unroll
        for (int i = 0; i < 4; ++i)
            async16(gA + kt + i * rowskip, l + i * 2048);
    };
    auto loadB = [&](short8 (&dst)[2][4], int kt) {
#pragma unroll
        for (int ks = 0; ks < 2; ++ks)
#pragma unroll
            for (int j = 0; j < 4; ++j)
                dst[ks][j] = *(const short8*)(bp[j] + kt + ks * 32);
    };
    auto compute = [&](int p, const short8 (&bfv)[2][4]) {
        const unsigned short* lb = ldsA[p];
#pragma unroll
        for (int ks = 0; ks < 2; ++ks) {
            short8 af[4];
#pragma unroll
            for (int i = 0; i < 4; ++i) {
                const int rowA = waveM + i * 16 + fm;
                af[i] = *(const short8*)(lb + rowA * 64 + (((ks << 2) + fq) ^ (rowA & 7)) * 8);
            }
#pragma unroll
            for (int i = 0; i < 4; ++i)
#pragma unroll
                for (int j = 0; j < 4; ++j)
                    acc[i][j] = __builtin_amdgcn_mfma_f32_16x16x32_bf16(
                        af[i], bfv[ks][j], acc[i][j], 0, 0, 0);
        }
    };

    short8 b0[2][4], b1[2][4];
    stageA(0, 0);
    loadB(b0, 0);

    // K = 2048, 16 outer iterations of 128
    for (int kt = 0; kt < K; kt += 128) {
        __syncthreads();                      // ldsA[0] ready
        stageA(kt + 64, 1);                   // kt+64 < K always (K % 128 == 0)
        loadB(b1, kt + 64);
        compute(0, b0);

        __syncthreads();                      // ldsA[1] ready
        if (kt + 128 < K) {
            stageA(kt + 128, 0);
            loadB(b0, kt + 128);
        }
        compute(1, b1);
    }

    // epilogue: C/D layout col = lane&15, row = (lane>>4)*4 + r
#pragma unroll
    for (int i = 0; i < 4; ++i) {
#pragma unroll
        for (int j = 0; j < 4; ++j) {
            const int col = bn + waveN + j * 16 + fm;
#pragma unroll
            for (int r = 0; r < 4; ++r) {
                const int row = bm + waveM + i * 16 + fq * 4 + r;
                out[(size_t)row * N + col] = acc[i][j][r] + bias[col];
            }
        }
    }
}

extern "C" void kernel_launch(void* const* d_in, const int* in_sizes, int n_in,
                              void* d_out, int out_size, void* d_ws, size_t ws_size,
                              hipStream_t stream) {
    const float* x      = (const float*)d_in[0];   // 4*4096*2048
    const float* angles = (const float*)d_in[1];   // 2096128
    const float* bias   = (const float*)d_in[2];   // 2048
    float* out = (float*)d_out;

    char* ws = (char*)d_ws;
    unsigned short* Abf = (unsigned short*)ws;                      //  8 MB: A bf16
    unsigned short* Wt  = (unsigned short*)(ws + (8u << 20));       //  8 MB: W^T bf16
    unsigned short* xbf = (unsigned short*)(ws + (16u << 20));      // 64 MB: x bf16

    const int M = 4 * 4096;
    const int n_elem_x = M * DIM;

    build_A_tiled<<<528, 256, 0, stream>>>(angles, Abf);
    cvt_f32_bf16<<<(n_elem_x / 4) / 256, 256, 0, stream>>>(x, xbf);

    // Wt = I - 2A - A*A^T  (2048^3, 1024 blocks)
    gemm_s64<<<dim3(DIM / 64, DIM / 64), 256, 0, stream>>>(Abf, Wt);

    // out = x @ W + bias  via NT against Wt  (16384 x 2048 x 2048)
    gemm_main<<<dim3(DIM / 128, M / 128), 256, 0, stream>>>(
        xbf, Wt, M, DIM, DIM, bias, out);
}